// Round 1
// baseline (363.887 us; speedup 1.0000x reference)
//
#include <hip/hip_runtime.h>
#include <math.h>

#define EPS_F 1e-5f
#define NPOINTS 550   // sum_{i=1..10} 10*i
#define CIN 512

// jax.nn.softplus(z) = max(z,0) + log1p(exp(-|z|))
static __device__ __forceinline__ float softplus_f(float z) {
    return fmaxf(z, 0.0f) + log1pf(expf(-fabsf(z)));
}

static __device__ __forceinline__ float dot8(const float4 a0, const float4 a1,
                                             const float4 w0, const float4 w1) {
    float s = a0.x * w0.x;
    s = fmaf(a0.y, w0.y, s);
    s = fmaf(a0.z, w0.z, s);
    s = fmaf(a0.w, w0.w, s);
    s = fmaf(a1.x, w1.x, s);
    s = fmaf(a1.y, w1.y, s);
    s = fmaf(a1.z, w1.z, s);
    s = fmaf(a1.w, w1.w, s);
    return s;
}

// Block = 256 threads (4 waves), 8 rows/wave -> 32 rows/block, grid 4096.
// v2: (a) all global loads issued BEFORE the tab build so HBM latency hides
// under the log2f work; barrier moved down to tab's first reader.
// (b) epilogue uses only compile-time indices into seg[] (rule #20: a
// runtime-indexed private array is demoted to scratch -> measured 5x).
__global__ __launch_bounds__(256, 4) void beta_unimodal_kernel(
    const float* __restrict__ x,
    const float* __restrict__ Wa, const float* __restrict__ ba,
    const float* __restrict__ Wb, const float* __restrict__ bb,
    float* __restrict__ out)
{
    __shared__ float2 tab[NPOINTS];          // (log2 g, log2(1-g)) per point
    __shared__ float outbuf[32 * 10];        // staged block output
    __shared__ float part[4][2][8][68];      // [wave][a/b][row][lane(+pad)]

    const int tid = threadIdx.x;
    const int lane = tid & 63;
    const int wave = tid >> 6;                            // 0..3
    const long rowBase = (long)blockIdx.x * 32 + wave * 8;

    // ---- Issue ALL global loads first: 4 x W float4 + 16 x row float4.
    // These fly while the tab build below does its transcendental work.
    const float4* Wa4 = (const float4*)Wa;
    const float4* Wb4 = (const float4*)Wb;
    const float4 wa0 = Wa4[lane], wa1 = Wa4[64 + lane];
    const float4 wb0 = Wb4[lane], wb1 = Wb4[64 + lane];

    float4 xv0[8], xv1[8];                   // static indices only (SROA-safe)
    #pragma unroll
    for (int r = 0; r < 8; ++r) {
        const float4* xr = (const float4*)(x + (rowBase + r) * CIN);
        xv0[r] = xr[lane];       // cols 0..255, 1KB/instr coalesced
        xv1[r] = xr[64 + lane];  // cols 256..511
    }

    // ---- Quadrature table build (overlaps the loads; no barrier yet) ----
    for (int p = tid; p < NPOINTS; p += 256) {
        int i = 1, off = 0;
        while (p >= off + 10 * i) { off += 10 * i; ++i; }
        const int j = p - off;
        const int n = 10 * i;
        const float thr = (float)i * 0.1f;
        const float step = (thr - 2.0f * EPS_F) / (float)(n - 1);
        const float g = EPS_F + step * (float)j;          // matches jnp.linspace f32
        float2 e;
        e.x = log2f(g);
        e.y = log2f(1.0f - g);
        tab[p] = e;
    }

    // ---- Phase 1: pure FMA on the prefetched rows ----
    float pa[8], pb[8];
    #pragma unroll
    for (int r = 0; r < 8; ++r) {
        pa[r] = dot8(xv0[r], xv1[r], wa0, wa1);
        pb[r] = dot8(xv0[r], xv1[r], wb0, wb1);
    }

    // ---- Per-wave LDS transpose reduction (wave-synchronous, no barrier) ----
    #pragma unroll
    for (int r = 0; r < 8; ++r) {
        part[wave][0][r][lane] = pa[r];   // 64 consecutive floats: conflict-free
        part[wave][1][r][lane] = pb[r];
    }
    asm volatile("s_waitcnt lgkmcnt(0)" ::: "memory");  // wave-synchronous LDS

    // 8 lanes per row: oct o = lane&7; o<4 sums a-quarter o, o>=4 b-quarter o-4
    const int row = lane >> 3;            // 0..7 (local row)
    const int o = lane & 7;
    const int v = o >> 2;                 // 0 = a, 1 = b
    const int qa = o & 3;                 // quarter of the 64 partials
    const float2* src2 = (const float2*)&part[wave][v][row][qa * 16];
    float s = 0.0f;
    #pragma unroll
    for (int c = 0; c < 8; ++c) {
        const float2 t = src2[c];
        s += t.x + t.y;
    }
    s += __shfl_xor(s, 1, 64);
    s += __shfl_xor(s, 2, 64);            // 4-lane set now holds full v-sum
    const float other = __shfl_xor(s, 4, 64);
    const float my_da = (v == 0) ? s : other;
    const float my_db = (v == 0) ? other : s;

    const float za = my_da + ba[0];
    const float zb = my_db + bb[0];
    const float alpha = fminf(fmaxf(1.0f + softplus_f(za), 1.0f), 100.0f);
    const float beta  = fminf(fmaxf(1.0f + softplus_f(zb), 1.0f), 100.0f);
    const float am1 = alpha - 1.0f;
    const float bm1 = beta - 1.0f;

    // Stabilizer at the Beta mode (lbeta & dx are common positive factors and
    // cancel in the normalization; concave exponent => all exp2 args <= 0).
    const float denom = am1 + bm1;
    float mode = (denom > 0.0f) ? (am1 / denom) : 0.5f;
    mode = fminf(fmaxf(mode, 1e-7f), 1.0f - 1.1920929e-7f);
    const float M2 = am1 * log2f(mode) + bm1 * log2f(1.0f - mode);

    __syncthreads();                      // tab now visible to all waves

    // ---- Phase 2: 8 lanes per row; lane o sums quadrature points j%8==o ----
    float seg[10];                        // static indices only -> registers
    int p0 = 0;
    #pragma unroll
    for (int i = 1; i <= 10; ++i) {
        const int n = 10 * i;
        float s2 = 0.0f;
        for (int j = o; j < n; j += 8) {  // broadcast LDS reads, conflict-free
            const float2 t = tab[p0 + j];
            const float e = fmaf(am1, t.x, bm1 * t.y) - M2;
            s2 += __builtin_amdgcn_exp2f(e);
        }
        s2 += __shfl_xor(s2, 1, 64);
        s2 += __shfl_xor(s2, 2, 64);
        s2 += __shfl_xor(s2, 4, 64);      // all 8 lanes of the row get full sum
        seg[i - 1] = s2;
        p0 += n;
    }

    const float inv = 1.0f / seg[9];
    const int rowLocal = wave * 8 + row;  // 0..31
    {   // Static-index epilogue: per-lane select via cndmask chain, then one
        // LDS store; lanes 0,1 also cover elements 8,9. Bitwise identical
        // values to the previous dynamic-index version.
        const float d0 = seg[0] * inv;
        const float d1 = (seg[1] - seg[0]) * inv;
        const float d2 = (seg[2] - seg[1]) * inv;
        const float d3 = (seg[3] - seg[2]) * inv;
        const float d4 = (seg[4] - seg[3]) * inv;
        const float d5 = (seg[5] - seg[4]) * inv;
        const float d6 = (seg[6] - seg[5]) * inv;
        const float d7 = (seg[7] - seg[6]) * inv;
        const float d8 = (seg[8] - seg[7]) * inv;
        const float d9 = (seg[9] - seg[8]) * inv;
        float mine = d0;
        mine = (o == 1) ? d1 : mine;
        mine = (o == 2) ? d2 : mine;
        mine = (o == 3) ? d3 : mine;
        mine = (o == 4) ? d4 : mine;
        mine = (o == 5) ? d5 : mine;
        mine = (o == 6) ? d6 : mine;
        mine = (o == 7) ? d7 : mine;
        outbuf[rowLocal * 10 + o] = mine;
        if (o < 2) {
            outbuf[rowLocal * 10 + 8 + o] = (o == 0) ? d8 : d9;
        }
    }
    __syncthreads();

    // ---- Coalesced block write: 320 floats = 80 float4 ----
    if (tid < 80) {
        const float4* src = (const float4*)outbuf;
        float4* dst = (float4*)(out + (size_t)blockIdx.x * 320);
        dst[tid] = src[tid];
    }
}

extern "C" void kernel_launch(void* const* d_in, const int* in_sizes, int n_in,
                              void* d_out, int out_size, void* d_ws, size_t ws_size,
                              hipStream_t stream) {
    const float* x  = (const float*)d_in[0];
    const float* Wa = (const float*)d_in[1];
    const float* ba = (const float*)d_in[2];
    const float* Wb = (const float*)d_in[3];
    const float* bb = (const float*)d_in[4];
    float* out = (float*)d_out;

    const int batch = in_sizes[0] / CIN;     // 131072
    const int blocks = batch / 32;           // 4096 blocks, 32 rows each
    beta_unimodal_kernel<<<blocks, 256, 0, stream>>>(x, Wa, ba, Wb, bb, out);
}